// Round 7
// baseline (323.129 us; speedup 1.0000x reference)
//
#include <hip/hip_runtime.h>

// CharBiLSTMEmbedder: N=32768 words, T=20, E=H=50, V=200, out [N,100] fp32.
//
// Round-7: (a) 1024-thr blocks: 16 waves/CU = 4 waves/SIMD (R6 had 2 -> VALU
// issue stalls exposed, VALUBusy 51%). 256 blocks = 1 round on 256 CUs; sorted
// wave-groups striped g = wv*128 + b so every block/SIMD gets a uniform length
// sample (balanced). LDS 149.3 KB: Gl 84.8 + Wa 26.6 + hs 32.8 + cs 5.1.
// (b) k_scan folded into k_scat (self-scan of the 2.7 KB histogram): 3 dispatches.

#define TT    20
#define HH    50
#define VV    200
#define TILES 13        // 13*16 = 208 rows >= 200
#define GSTR  212       // G LDS row stride in shorts (53 units * 4 gates)
#define GSH   (VV * GSTR)        // 42400 shorts per dir
#define WSH   (TILES * 16 * 64)  // 13312 shorts per dir
#define NW    32768
#define NB_G  332       // ceil(2*GSH/256)
#define NB_W  104       // ceil(2*WSH/256)
#define NB_H  128       // 128*256 = 32768 words

typedef __attribute__((ext_vector_type(8))) short bf16x8;
typedef __attribute__((ext_vector_type(4))) short s16x4;
typedef __attribute__((ext_vector_type(4))) float f32x4;

__device__ __forceinline__ float frcp(float x) { return __builtin_amdgcn_rcpf(x); }
__device__ __forceinline__ float fsig(float x) { return frcp(1.0f + __expf(-x)); }
__device__ __forceinline__ float ftanhf(float x) { return 1.0f - 2.0f * frcp(1.0f + __expf(2.0f * x)); }

__device__ __forceinline__ short f2bf(float x) {  // RNE fp32 -> bf16
    unsigned b = __builtin_bit_cast(unsigned, x);
    unsigned r = (b + 0x7FFFu + ((b >> 16) & 1u)) >> 16;
    return (short)r;
}
__device__ __forceinline__ float bf2f(short s) {
    return __builtin_bit_cast(float, ((unsigned)(unsigned short)s) << 16);
}

// One kernel, three jobs by block range:
//  [0,NB_G): Gimg[d][v*GSTR+u*4+g] = bf16(emb'[v].W_ih[g*50+u] + b_ih + b_hh)
//  [NB_G,NB_G+NB_W): Wimg = MFMA A-operand image of Whh (bf16, k-swizzled)
//  [NB_G+NB_W, +NB_H): cnt[block][21] = length histogram of 256 words
__global__ void k_prep(const float* __restrict__ emb,
                       const float* __restrict__ Wih_f, const float* __restrict__ bih_f,
                       const float* __restrict__ bhh_f,
                       const float* __restrict__ Wih_b, const float* __restrict__ bih_b,
                       const float* __restrict__ bhh_b,
                       const float* __restrict__ Whh_f, const float* __restrict__ Whh_b,
                       const int* __restrict__ lens,
                       short* __restrict__ Gimg, short* __restrict__ Wimg,
                       int* __restrict__ cnt) {
    int blk = blockIdx.x;
    int tid = threadIdx.x;
    if (blk < NB_G) {
        int idx = blk * 256 + tid;
        if (idx >= 2 * GSH) return;
        int d = idx / GSH;
        int rem = idx % GSH;
        int v = rem / GSTR;
        int u = (rem % GSTR) >> 2;
        int g = idx & 3;
        if (u >= HH) { Gimg[idx] = 0; return; }
        int r = g * HH + u;
        const float* Wih = d ? Wih_b : Wih_f;
        const float* bih = d ? bih_b : bih_f;
        const float* bhh = d ? bhh_b : bhh_f;
        float s = bih[r] + bhh[r];
        if (v != 0) {  // PAD row of emb is zero
            #pragma unroll 10
            for (int e = 0; e < HH; ++e) s = fmaf(emb[v * HH + e], Wih[r * HH + e], s);
        }
        Gimg[idx] = f2bf(s);
    } else if (blk < NB_G + NB_W) {
        int idx = (blk - NB_G) * 256 + tid;
        if (idx >= 2 * WSH) return;
        int d = idx / WSH;
        int e = idx % WSH;
        int t = e >> 10, m = (e >> 6) & 15, k = e & 63;
        int u = 4 * t + (m >> 2), g = m & 3;
        const float* Whh = d ? Whh_b : Whh_f;
        float val = (k < HH && u < HH) ? Whh[(g * HH + u) * HH + k] : 0.0f;
        int ksw = (k & 7) | (((k >> 3) ^ (m & 7)) << 3);
        Wimg[d * WSH + (e & ~63) + ksw] = f2bf(val);
    } else {
        int hb = blk - NB_G - NB_W;      // 0..127
        __shared__ int hcnt[21];
        if (tid < 21) hcnt[tid] = 0;
        __syncthreads();
        atomicAdd(&hcnt[lens[hb * 256 + tid]], 1);
        __syncthreads();
        if (tid < 21) cnt[hb * 21 + tid] = hcnt[tid];
    }
}

// Self-scanning scatter: each block recomputes global bucket starts from cnt
// (2.7 KB, L2-hot) then scatters its 256 words. Buckets ordered L=20..0.
__global__ void k_scat(const int* __restrict__ lens, const int* __restrict__ cnt,
                       int* __restrict__ perm) {
    __shared__ int tots[21], before_s[21], cur[21];
    int b = blockIdx.x, t = threadIdx.x;
    if (t < 21) {
        int before = 0, tot = 0;
        for (int bb = 0; bb < NB_H; ++bb) {
            int c = cnt[bb * 21 + t];
            before += (bb < b) ? c : 0;
            tot += c;
        }
        tots[t] = tot;
        before_s[t] = before;
    }
    __syncthreads();
    if (t < 21) {
        int start = 0;
        for (int L = 20; L > t; --L) start += tots[L];
        cur[t] = start + before_s[t];
    }
    __syncthreads();
    int i = b * 256 + t;
    int pos = atomicAdd(&cur[lens[i]], 1);
    perm[pos] = i;
}

__launch_bounds__(1024, 4)
__global__ void k_lstm(const int* __restrict__ chars, const int* __restrict__ lens,
                       const int* __restrict__ perm,
                       const short* __restrict__ Gimg, const short* __restrict__ Wimg,
                       float* __restrict__ out) {
    __shared__ __align__(16) short Wa[WSH];        // 26624 B
    __shared__ __align__(16) short Gl[GSH];        // 84800 B
    __shared__ __align__(16) short hs[16][1024];   // per-wave h (bf16, swizzled)
    __shared__ unsigned char cs[16][320];          // per-wave chars (u8)

    int gb   = blockIdx.x;         // 0..255
    int d    = gb & 1;
    int b    = gb >> 1;            // 0..127
    int tid  = threadIdx.x;        // 0..1023
    int lane = tid & 63;
    int wv   = __builtin_amdgcn_readfirstlane(tid >> 6);   // 0..15
    int quad = lane >> 4;
    int n    = lane & 15;
    int x7   = n & 7;

    // ---- stage: coalesced block copies ----
    {
        const int4* src = (const int4*)(Wimg + d * WSH);
        int4* dst = (int4*)Wa;
        for (int i = tid; i < WSH / 8; i += 1024) dst[i] = src[i];
    }
    {
        const int4* src = (const int4*)(Gimg + d * GSH);
        int4* dst = (int4*)Gl;
        for (int i = tid; i < GSH / 8; i += 1024) dst[i] = src[i];
    }
    {
        int4 z = {0, 0, 0, 0};
        int4* hz = (int4*)&hs[0][0];
        for (int i = tid; i < 16 * 1024 / 8; i += 1024) hz[i] = z;
    }
    // striped sorted-group assignment: every block/SIMD gets a uniform
    // sample of the length distribution -> balanced makespan
    int g = wv * 128 + b;                      // 0..2047
    int slotbase = g * 16;
    {   // wave's 16 words x 20 chars -> u8 LDS (words scattered via perm)
        for (int i = lane; i < 16 * TT; i += 64) {
            int w = perm[slotbase + i / TT];
            cs[wv][i] = (unsigned char)chars[w * TT + i % TT];
        }
    }
    __syncthreads();

    int word = perm[slotbase + n];
    int L = lens[word];
    int mL = L;
    #pragma unroll
    for (int off = 8; off; off >>= 1) {
        int t2 = __shfl_xor(mL, off);
        mL = mL > t2 ? mL : t2;
    }
    mL = __builtin_amdgcn_readfirstlane(mL);

    const bf16x8* ap = (const bf16x8*)Wa;
    const bf16x8* bp = (const bf16x8*)hs[wv];
    short* hw = hs[wv];
    const unsigned char* cw = cs[wv] + n * TT;

    int pa0 = quad ^ x7;           // swizzled k-group, k 0..31
    int pa1 = (quad + 4) ^ x7;     // k 32..63

    float cst[TILES], hf[TILES];
    #pragma unroll
    for (int t = 0; t < TILES; ++t) { cst[t] = 0.0f; hf[t] = 0.0f; }

    #pragma unroll 1
    for (int s = 0; s < mL; ++s) {
        bool valid = s < L;
        int p = valid ? (d ? (L - 1 - s) : s) : 0;
        int v = cw[p];

        bf16x8 B0 = bp[n * 8 + pa0];     // h of step s-1, B-operand layout
        bf16x8 B1 = bp[n * 8 + pa1];

        // pass 1: MFMAs; acc init = bf16 G from LDS (char preactivation)
        f32x4 acc[TILES];
        #pragma unroll
        for (int t = 0; t < TILES; ++t) {
            int u = 4 * t + quad;
            s16x4 gv = *(const s16x4*)&Gl[v * GSTR + u * 4];
            f32x4 a;
            a[0] = bf2f(gv[0]); a[1] = bf2f(gv[1]);
            a[2] = bf2f(gv[2]); a[3] = bf2f(gv[3]);
            bf16x8 A0 = ap[(t * 16 + n) * 8 + pa0];
            bf16x8 A1 = ap[(t * 16 + n) * 8 + pa1];
            a = __builtin_amdgcn_mfma_f32_16x16x32_bf16(A0, B0, a, 0, 0, 0);
            a = __builtin_amdgcn_mfma_f32_16x16x32_bf16(A1, B1, a, 0, 0, 0);
            acc[t] = a;
        }
        // pass 2: lane-local gate math; h back to LDS in bf16
        #pragma unroll
        for (int t = 0; t < TILES; ++t) {
            int u = 4 * t + quad;
            float ig = fsig(acc[t][0]);
            float fg = fsig(acc[t][1]);
            float gg = ftanhf(acc[t][2]);
            float og = fsig(acc[t][3]);
            float cold = cst[t];
            float cn = fg * cold + ig * gg;
            float hn = og * ftanhf(cn);
            bool upd = valid && (u < HH);
            cst[t] = upd ? cn : cold;
            hf[t]  = upd ? hn : hf[t];
            if (upd) {
                int idx = n * 64 + (((u >> 3) ^ x7) << 3) + (u & 7);
                hw[idx] = f2bf(hn);      // skipped when invalid -> h frozen
            }
        }
    }

    float* orow = out + (size_t)word * (2 * HH) + d * HH;
    #pragma unroll
    for (int t = 0; t < TILES; ++t) {
        int u = 4 * t + quad;
        if (u < HH) orow[u] = hf[t];     // fp32 h
    }
}

extern "C" void kernel_launch(void* const* d_in, const int* in_sizes, int n_in,
                              void* d_out, int out_size, void* d_ws, size_t ws_size,
                              hipStream_t stream) {
    const int*   chars = (const int*)d_in[0];
    const int*   lens  = (const int*)d_in[1];
    const float* emb   = (const float*)d_in[2];
    const float* Wih_f = (const float*)d_in[3];
    const float* Whh_f = (const float*)d_in[4];
    const float* bih_f = (const float*)d_in[5];
    const float* bhh_f = (const float*)d_in[6];
    const float* Wih_b = (const float*)d_in[7];
    const float* Whh_b = (const float*)d_in[8];
    const float* bih_b = (const float*)d_in[9];
    const float* bhh_b = (const float*)d_in[10];
    float* out = (float*)d_out;

    short* Gimg = (short*)d_ws;                 // 169600 B
    short* Wimg = Gimg + 2 * GSH;               //  53248 B
    int*   cnt  = (int*)(Wimg + 2 * WSH);       //  10752 B
    int*   perm = cnt + NB_H * 21;              // 131072 B

    k_prep<<<NB_G + NB_W + NB_H, 256, 0, stream>>>(emb, Wih_f, bih_f, bhh_f,
                                                   Wih_b, bih_b, bhh_b,
                                                   Whh_f, Whh_b, lens,
                                                   Gimg, Wimg, cnt);
    k_scat<<<NB_H, 256, 0, stream>>>(lens, cnt, perm);
    k_lstm<<<256, 1024, 0, stream>>>(chars, lens, perm, Gimg, Wimg, out);
}